// Round 10
// baseline (436.211 us; speedup 1.0000x reference)
//
#include <hip/hip_runtime.h>
#include <string.h>

typedef unsigned short u16;
typedef unsigned int u32;
typedef __bf16 bf16x8 __attribute__((ext_vector_type(8)));
typedef float f32x4 __attribute__((ext_vector_type(4)));
typedef float f32x16 __attribute__((ext_vector_type(16)));
typedef u16 us8 __attribute__((ext_vector_type(8)));
typedef u16 us4 __attribute__((ext_vector_type(4)));
typedef u32 uu4 __attribute__((ext_vector_type(4)));

#define DEVINL __device__ __forceinline__

static constexpr int Bn = 4, Sn = 2048, Dn = 1024, Hn = 16;
static constexpr float LOG2E = 1.4426950408889634f;

DEVINL u16 f2bf(float f) {
  __bf16 h = (__bf16)f;
  u16 u;
  memcpy(&u, &h, 2);
  return u;
}

DEVINL void gload16(const void* g, void* l) {
  __builtin_amdgcn_global_load_lds((const __attribute__((address_space(1))) void*)g,
                                   (__attribute__((address_space(3))) void*)l, 16, 0, 0);
}

// tiles are [rows][64 bf16] = [rows][128B]; XOR-swizzle 16B chunks within the row
DEVINL unsigned swz(unsigned row, unsigned kbyte) {
  return row * 128u + (kbyte ^ ((row & 7u) << 4));
}

DEVINL bf16x8 lds8(const u16* base, unsigned byteoff) {
  return *(const bf16x8*)((const char*)base + byteoff);
}

DEVINL u32 cvtpk(float a, float b) {
  u32 r;
  asm("v_cvt_pk_bf16_f32 %0, %1, %2" : "=v"(r) : "v"(a), "v"(b));
  return r;
}

// swap: x.lanes[32:63] <-> y.lanes[0:31]
DEVINL void permswap(u32& x, u32& y) {
  asm("v_permlane32_swap_b32 %0, %1" : "+v"(x), "+v"(y));
}

// ---------------- fused fp32->bf16 convert (q,k,v) + mask scan (z=3) ---------
__global__ __launch_bounds__(256) void cvt_all(const float* __restrict__ q, const float* __restrict__ k,
                                               const float* __restrict__ v, const float* __restrict__ mask,
                                               u16* __restrict__ oq, u16* __restrict__ ok,
                                               u16* __restrict__ ov, int* __restrict__ flag) {
  int z = blockIdx.y;
  if (z == 3) {
    size_t i = ((size_t)blockIdx.x * 256 + threadIdx.x) * 4;
    float4 m = *(const float4*)(mask + i);
    bool nz = (m.x != 0.f) || (m.y != 0.f) || (m.z != 0.f) || (m.w != 0.f);
    if (nz) atomicOr(flag, 1);
    return;
  }
  const float* in = z == 0 ? q : (z == 1 ? k : v);
  u16* out = z == 0 ? oq : (z == 1 ? ok : ov);
  size_t i = ((size_t)blockIdx.x * 256 + threadIdx.x) * 8;
  float4 a = *(const float4*)(in + i);
  float4 b = *(const float4*)(in + i + 4);
  us8 o;
  o[0] = f2bf(a.x); o[1] = f2bf(a.y); o[2] = f2bf(a.z); o[3] = f2bf(a.w);
  o[4] = f2bf(b.x); o[5] = f2bf(b.y); o[6] = f2bf(b.z); o[7] = f2bf(b.w);
  *(us8*)(out + i) = o;
}

// ---------------- fused W [K][N] fp32 -> Wt [N][K] bf16 (all 4 weights) ------
__global__ __launch_bounds__(256) void cvt_w_all(const float* __restrict__ w0, const float* __restrict__ w1,
                                                 const float* __restrict__ w2, const float* __restrict__ w3,
                                                 u16* __restrict__ t0, u16* __restrict__ t1,
                                                 u16* __restrict__ t2, u16* __restrict__ t3) {
  int z = blockIdx.z;
  const float* W = z == 0 ? w0 : (z == 1 ? w1 : (z == 2 ? w2 : w3));
  u16* Wt = z == 0 ? t0 : (z == 1 ? t1 : (z == 2 ? t2 : t3));
  __shared__ float T[32][33];
  int n0 = blockIdx.x * 32, k0 = blockIdx.y * 32;
  int tx = threadIdx.x & 31, ty = threadIdx.x >> 5;
#pragma unroll
  for (int r = 0; r < 4; r++)
    T[ty + r * 8][tx] = W[(size_t)(k0 + ty + r * 8) * 1024 + n0 + tx];
  __syncthreads();
#pragma unroll
  for (int r = 0; r < 4; r++)
    Wt[(size_t)(n0 + ty + r * 8) * 1024 + k0 + tx] = f2bf(T[tx][ty + r * 8]);
}

// ---------------- V [B,S,D] bf16 -> Vt [B,H,64,S] bf16 (plain transpose) -----
__global__ __launch_bounds__(256) void transpose_v(const u16* __restrict__ V, u16* __restrict__ Vt) {
  __shared__ u16 T[64][72];
  int s0 = blockIdx.x * 64;
  int b = blockIdx.y >> 4, h = blockIdx.y & 15;
  int tid = threadIdx.x;
#pragma unroll
  for (int it = 0; it < 2; it++) {
    int chunk = it * 256 + tid;
    int s = chunk >> 3, c = chunk & 7;
    us8 v = *(const us8*)&V[((size_t)(b * Sn + s0 + s)) * Dn + h * 64 + c * 8];
#pragma unroll
    for (int j = 0; j < 8; j++) T[c * 8 + j][s] = v[j];
  }
  __syncthreads();
#pragma unroll
  for (int it = 0; it < 2; it++) {
    int chunk = it * 256 + tid;
    int dk = chunk >> 3, c = chunk & 7;
    us8 o = *(const us8*)&T[dk][c * 8];
    *(us8*)&Vt[((size_t)((b * Hn + h) * 64 + dk)) * Sn + s0 + c * 8] = o;
  }
}

// ---------------- GEMM core (m97 structure, 128x128 tile, BK=64) -------------
template <int EPI>  // 0: bf16 out *alpha; 1: fp32 out + residual
DEVINL void gemm_body(const u16* __restrict__ A, const u16* __restrict__ Bt, void* __restrict__ Cout,
                      const float* __restrict__ resid, float alpha, u16* As, u16* Bs, int m0, int n0) {
  constexpr int K = 1024, N = 1024;
  int tid = threadIdx.x, w = tid >> 6, l = tid & 63;
  int wr = w >> 1, wc = w & 1;
  int l15 = l & 15, l4 = l >> 4;
  int lrow8 = l >> 3;
  int chunk = (l & 7) ^ (lrow8 & 7);

  f32x4 acc[4][4];
#pragma unroll
  for (int i = 0; i < 4; i++)
#pragma unroll
    for (int j = 0; j < 4; j++)
#pragma unroll
      for (int r = 0; r < 4; r++) acc[i][j][r] = 0.f;

  for (int kt = 0; kt < K; kt += 64) {
    __syncthreads();
#pragma unroll
    for (int c = 0; c < 4; c++) {
      int rowb = w * 32 + c * 8;
      int row = rowb + lrow8;
      gload16(&A[(size_t)(m0 + row) * K + kt + chunk * 8], &As[rowb * 64]);
      gload16(&Bt[(size_t)(n0 + row) * K + kt + chunk * 8], &Bs[rowb * 64]);
    }
    __syncthreads();
#pragma unroll
    for (int kk = 0; kk < 2; kk++) {
      bf16x8 af[4], bfr[4];
#pragma unroll
      for (int i = 0; i < 4; i++) {
        af[i] = lds8(As, swz(wr * 64 + i * 16 + l15, kk * 64 + l4 * 16));
        bfr[i] = lds8(Bs, swz(wc * 64 + i * 16 + l15, kk * 64 + l4 * 16));
      }
#pragma unroll
      for (int mi = 0; mi < 4; mi++)
#pragma unroll
        for (int ni = 0; ni < 4; ni++)
          acc[mi][ni] = __builtin_amdgcn_mfma_f32_16x16x32_bf16(af[mi], bfr[ni], acc[mi][ni], 0, 0, 0);
    }
  }

#pragma unroll
  for (int mi = 0; mi < 4; mi++)
#pragma unroll
    for (int ni = 0; ni < 4; ni++)
#pragma unroll
      for (int r = 0; r < 4; r++) {
        int row = m0 + wr * 64 + mi * 16 + l4 * 4 + r;
        int col = n0 + wc * 64 + ni * 16 + l15;
        float v = acc[mi][ni][r] * alpha;
        if constexpr (EPI == 0) {
          ((u16*)Cout)[(size_t)row * N + col] = f2bf(v);
        } else {
          ((float*)Cout)[(size_t)row * N + col] = v + resid[(size_t)row * N + col];
        }
      }
}

// XCD-aware remap of a 512-block (8 n x 64 m) grid: same-XCD blocks contiguous
DEVINL void swizzled_tiles(int& m0, int& n0) {
  int lin = blockIdx.y * 8 + blockIdx.x;
  int sl = (lin & 7) * 64 + (lin >> 3);
  n0 = (sl & 7) * 128;
  m0 = (sl >> 3) * 128;
}

// fused Q/K/V projections: one dispatch, z selects matrices (1536 blocks)
__global__ __launch_bounds__(256) void gemm_qkv(const u16* __restrict__ Aq, const u16* __restrict__ Ak,
                                                const u16* __restrict__ Av, const u16* __restrict__ Wtq,
                                                const u16* __restrict__ Wtk, const u16* __restrict__ Wtv,
                                                u16* __restrict__ Cq, u16* __restrict__ Ck,
                                                u16* __restrict__ Cv, float alphaq) {
  __shared__ u16 As[128 * 64];
  __shared__ u16 Bs[128 * 64];
  int z = blockIdx.z;
  const u16* A = z == 0 ? Aq : (z == 1 ? Ak : Av);
  const u16* Bt = z == 0 ? Wtq : (z == 1 ? Wtk : Wtv);
  u16* C = z == 0 ? Cq : (z == 1 ? Ck : Cv);
  float alpha = z == 0 ? alphaq : 1.0f;
  int m0, n0;
  swizzled_tiles(m0, n0);
  gemm_body<0>(A, Bt, C, nullptr, alpha, As, Bs, m0, n0);
}

// output projection + residual (fp32 out)
__global__ __launch_bounds__(256) void gemm_o(const u16* __restrict__ A, const u16* __restrict__ Bt,
                                              float* __restrict__ Cout, const float* __restrict__ resid) {
  __shared__ u16 As[128 * 64];
  __shared__ u16 Bs[128 * 64];
  int m0, n0;
  swizzled_tiles(m0, n0);
  gemm_body<1>(A, Bt, Cout, resid, 1.0f, As, Bs, m0, n0);
}

// ---------------- flash attention: 8-wave, 64 q/wave, 4-way kv parity --------
// Q: [B,S,D] bf16 pre-scaled by log2e/8. K: [B,S,D] bf16.
// Vt: [B,H,64,S] bf16 (plain transpose). Out: [B,S,D] bf16.
// 512 threads: wave w -> q-half qg2 = w&1 (64 q rows: 2 groups of 32),
// kv parity p = w>>1 (tiles 4j+p). Swapped QK^T (A=K, B=Q): lane's
// sc[g][r] = P[kv = kvt*32+crow(r,hi)][q = l31 of group g]. Each kf/vf LDS
// read feeds BOTH q-groups -> per-q-row LDS traffic halved vs round 9.
// P -> PV A-operand in-register (cvt_pk + permlane32_swap). Row sums are
// lane-local scalars (swapped layout) + one shfl_xor(32).
// 4-parity partials combined through the 64KB LDS in two dt-rounds.
__global__ __launch_bounds__(512, 2) void attn_k(const u16* __restrict__ Qb, const u16* __restrict__ Kb,
                                                 const u16* __restrict__ Vt, const float* __restrict__ mask,
                                                 const int* __restrict__ flag, u16* __restrict__ Ob) {
  __shared__ u16 SH[8 * 4096];  // [p]=K bufs, [4+p]=V bufs; epilogue: fp32 scratch
  int tid = threadIdx.x, w = tid >> 6, l = tid & 63;
  int qg2 = w & 1, p = w >> 1;
  int l31 = l & 31, hi = l >> 5;
  int b = blockIdx.y >> 4, h = blockIdx.y & 15;
  int q0 = blockIdx.x * 128;
  int lrow8 = l >> 3;
  int chunk = (l & 7) ^ (lrow8 & 7);

  u16* Kp = SH + p * 4096;
  u16* Vp = SH + (4 + p) * 4096;

  // Q fragments (B-operand), 2 groups x 4 k-slots: q = l31, d = ks*16 + hi*8 + j
  bf16x8 qf[2][4];
#pragma unroll
  for (int g = 0; g < 2; g++) {
    const u16* qp = &Qb[((size_t)(b * Sn + q0 + qg2 * 64 + g * 32 + l31)) * Dn + h * 64 + hi * 8];
#pragma unroll
    for (int ks = 0; ks < 4; ks++) qf[g][ks] = *(const bf16x8*)(qp + ks * 16);
  }

  float run_s[2] = {0.f, 0.f};  // per-lane partial row sums (q = l31 of group g)
  f32x16 acc[2][2];             // [g][dt]: col d = dt*32+l31, row q = crow(r,hi)
#pragma unroll
  for (int g = 0; g < 2; g++)
#pragma unroll
    for (int dt = 0; dt < 2; dt++)
#pragma unroll
      for (int r = 0; r < 16; r++) acc[g][dt][r] = 0.f;

  int msk = *flag;

  const size_t kbase = (size_t)b * Sn * Dn + h * 64 + chunk * 8;
  const size_t vbase = (size_t)(b * Hn + h) * 64 * Sn + chunk * 8;

  for (int j = 0; j < 8; j++) {
    int kv0 = (4 * j + p) * 64;
    __syncthreads();  // all waves done reading previous tiles
    // stage: the 2 waves of parity p cover 64 rows of K and V (32 each)
#pragma unroll
    for (int c = 0; c < 4; c++) {
      int rowb = qg2 * 32 + c * 8;
      int rr = rowb + lrow8;
      gload16(Kb + kbase + (size_t)(kv0 + rr) * Dn, &Kp[rowb * 64]);
      gload16(Vt + vbase + (size_t)rr * Sn + kv0, &Vp[rowb * 64]);
    }
    __syncthreads();  // tiles resident (vmcnt drained before barrier)

#pragma unroll
    for (int kvt = 0; kvt < 2; kvt++) {
      // swapped QK^T: one kf read feeds both q-groups
      f32x16 sc[2];
#pragma unroll
      for (int g = 0; g < 2; g++)
#pragma unroll
        for (int r = 0; r < 16; r++) sc[g][r] = 0.f;
#pragma unroll
      for (int ks = 0; ks < 4; ks++) {
        bf16x8 kf = lds8(Kp, swz(kvt * 32 + l31, ks * 32 + hi * 16));
        sc[0] = __builtin_amdgcn_mfma_f32_32x32x16_bf16(kf, qf[0][ks], sc[0], 0, 0, 0);
        sc[1] = __builtin_amdgcn_mfma_f32_32x32x16_bf16(kf, qf[1][ks], sc[1], 0, 0, 0);
      }

      if (msk) {
#pragma unroll
        for (int g = 0; g < 2; g++) {
          const float* mp =
              mask + ((size_t)b * Sn + (q0 + qg2 * 64 + g * 32 + l31)) * Sn + kv0 + kvt * 32;
#pragma unroll
          for (int r = 0; r < 16; r++) {
            int kvl = (r & 3) + 8 * (r >> 2) + 4 * hi;
            sc[g][r] += mp[kvl] * LOG2E;
          }
        }
      }

      // P = exp2(sc); per-lane partial sums; pack PV A-fragments in-register
      bf16x8 pa[2][2];
#pragma unroll
      for (int g = 0; g < 2; g++) {
#pragma unroll
        for (int r = 0; r < 16; r++) {
          float pv = exp2f(sc[g][r]);
          run_s[g] += pv;
          sc[g][r] = pv;
        }
#pragma unroll
        for (int s = 0; s < 2; s++) {
          int rb = s * 8;
          u32 x0 = cvtpk(sc[g][rb + 0], sc[g][rb + 1]);
          u32 y0 = cvtpk(sc[g][rb + 4], sc[g][rb + 5]);
          u32 x1 = cvtpk(sc[g][rb + 2], sc[g][rb + 3]);
          u32 y1 = cvtpk(sc[g][rb + 6], sc[g][rb + 7]);
          permswap(x0, y0);
          permswap(x1, y1);
          uu4 wv;
          wv[0] = x0; wv[1] = x1; wv[2] = y0; wv[3] = y1;
          pa[g][s] = *(bf16x8*)&wv;
        }
      }

      // PV: one vf read feeds both q-groups
#pragma unroll
      for (int dt = 0; dt < 2; dt++) {
        bf16x8 vf0 = lds8(Vp, swz(dt * 32 + l31, (2 * kvt) * 32 + hi * 16));
        bf16x8 vf1 = lds8(Vp, swz(dt * 32 + l31, (2 * kvt + 1) * 32 + hi * 16));
        acc[0][dt] = __builtin_amdgcn_mfma_f32_32x32x16_bf16(pa[0][0], vf0, acc[0][dt], 0, 0, 0);
        acc[0][dt] = __builtin_amdgcn_mfma_f32_32x32x16_bf16(pa[0][1], vf1, acc[0][dt], 0, 0, 0);
        acc[1][dt] = __builtin_amdgcn_mfma_f32_32x32x16_bf16(pa[1][0], vf0, acc[1][dt], 0, 0, 0);
        acc[1][dt] = __builtin_amdgcn_mfma_f32_32x32x16_bf16(pa[1][1], vf1, acc[1][dt], 0, 0, 0);
      }
    }
  }

  // ---- epilogue: combine 4 parity partials through LDS (2 dt-rounds) ----
  run_s[0] += __shfl_xor(run_s[0], 32);  // complete kv coverage across hi-halves
  run_s[1] += __shfl_xor(run_s[1], 32);
  __syncthreads();  // main-loop LDS reads done; SH reusable as fp32 scratch
  float* Xf = (float*)SH;  // 16384 floats
  int wid = (p - 1) * 2 + qg2;  // writer index 0..5 (parities 1..3)

  if (p != 0) {  // round A: dt=0 partials + run_s
#pragma unroll
    for (int g = 0; g < 2; g++) {
#pragma unroll
      for (int r = 0; r < 16; r++) Xf[(wid * 2 + g) * 1024 + r * 64 + l] = acc[g][0][r];
      Xf[12288 + (wid * 2 + g) * 64 + l] = run_s[g];
    }
  }
  __syncthreads();
  if (p == 0) {
#pragma unroll
    for (int pp = 0; pp < 3; pp++) {
      int wr_ = pp * 2 + qg2;
#pragma unroll
      for (int g = 0; g < 2; g++) {
#pragma unroll
        for (int r = 0; r < 16; r++) acc[g][0][r] += Xf[(wr_ * 2 + g) * 1024 + r * 64 + l];
        run_s[g] += Xf[12288 + (wr_ * 2 + g) * 64 + l];
      }
    }
  }
  __syncthreads();
  if (p != 0) {  // round B: dt=1 partials
#pragma unroll
    for (int g = 0; g < 2; g++)
#pragma unroll
      for (int r = 0; r < 16; r++) Xf[(wid * 2 + g) * 1024 + r * 64 + l] = acc[g][1][r];
  }
  __syncthreads();
  if (p == 0) {
#pragma unroll
    for (int pp = 0; pp < 3; pp++) {
      int wr_ = pp * 2 + qg2;
#pragma unroll
      for (int g = 0; g < 2; g++)
#pragma unroll
        for (int r = 0; r < 16; r++) acc[g][1][r] += Xf[(wr_ * 2 + g) * 1024 + r * 64 + l];
    }
    // normalize + store (inv lives in lane q = crow(r,hi); pull via shfl)
#pragma unroll
    for (int g = 0; g < 2; g++) {
      float inv = 1.0f / run_s[g];
#pragma unroll
      for (int r = 0; r < 16; r++) {
        int ql = (r & 3) + 8 * (r >> 2) + 4 * hi;
        float invq = __shfl(inv, ql);
        int row = q0 + qg2 * 64 + g * 32 + ql;
#pragma unroll
        for (int dt = 0; dt < 2; dt++) {
          int col = h * 64 + dt * 32 + l31;
          Ob[((size_t)(b * Sn + row)) * Dn + col] = f2bf(acc[g][dt][r] * invq);
        }
      }
    }
  }
}

// ---------------- residual + LayerNorm (fp32 output) -------------------------
__global__ __launch_bounds__(256) void ln_k(const float* __restrict__ y, const float* __restrict__ gamma,
                                            const float* __restrict__ beta, float* __restrict__ out) {
  int row = blockIdx.x;
  int tid = threadIdx.x;
  const float* p = y + (size_t)row * 1024 + tid * 4;
  float4 v = *(const float4*)p;
  float s = v.x + v.y + v.z + v.w;
  float ss = v.x * v.x + v.y * v.y + v.z * v.z + v.w * v.w;
#pragma unroll
  for (int off = 1; off < 64; off <<= 1) {
    s += __shfl_xor(s, off);
    ss += __shfl_xor(ss, off);
  }
  __shared__ float rs_[4], rss_[4];
  int w = tid >> 6, l = tid & 63;
  if (l == 0) { rs_[w] = s; rss_[w] = ss; }
  __syncthreads();
  s = rs_[0] + rs_[1] + rs_[2] + rs_[3];
  ss = rss_[0] + rss_[1] + rss_[2] + rss_[3];
  float mean = s * (1.f / 1024.f);
  float var = ss * (1.f / 1024.f) - mean * mean;
  float rstd = rsqrtf(var + 1e-6f);
  float4 g = *(const float4*)(gamma + tid * 4);
  float4 bb = *(const float4*)(beta + tid * 4);
  float4 o;
  o.x = (v.x - mean) * rstd * g.x + bb.x;
  o.y = (v.y - mean) * rstd * g.y + bb.y;
  o.z = (v.z - mean) * rstd * g.z + bb.z;
  o.w = (v.w - mean) * rstd * g.w + bb.w;
  *(float4*)(out + (size_t)row * 1024 + tid * 4) = o;
}

// ---------------- launch -----------------------------------------------------
extern "C" void kernel_launch(void* const* d_in, const int* in_sizes, int n_in,
                              void* d_out, int out_size, void* d_ws, size_t ws_size,
                              hipStream_t stream) {
  const float* query = (const float*)d_in[0];
  const float* key_ = (const float*)d_in[1];
  const float* value = (const float*)d_in[2];
  const float* mask = (const float*)d_in[3];
  const float* Wq = (const float*)d_in[4];
  const float* Wk = (const float*)d_in[5];
  const float* Wv = (const float*)d_in[6];
  const float* Wo = (const float*)d_in[7];
  const float* gamma = (const float*)d_in[8];
  const float* beta = (const float*)d_in[9];

  char* ws = (char*)d_ws;
  int* flag = (int*)ws;
  size_t off = 256;
  u16* Wtq = (u16*)(ws + off); off += (size_t)1024 * 1024 * 2;
  u16* Wtk = (u16*)(ws + off); off += (size_t)1024 * 1024 * 2;
  u16* Wtv = (u16*)(ws + off); off += (size_t)1024 * 1024 * 2;
  u16* Wto = (u16*)(ws + off); off += (size_t)1024 * 1024 * 2;
  const size_t TOK = (size_t)8192 * 1024;
  u16* Qb = (u16*)(ws + off); off += TOK * 2;
  u16* Kb = (u16*)(ws + off); off += TOK * 2;
  u16* Vb = (u16*)(ws + off); off += TOK * 2;
  u16* Vt = (u16*)(ws + off); off += TOK * 2;
  u16* Xq = (u16*)(ws + off); off += TOK * 2;
  u16* Xk = (u16*)(ws + off); off += TOK * 2;
  u16* Xv = (u16*)(ws + off); off += TOK * 2;
  u16* attnX = Xq;        // alias: Xq dead after Q projection
  float* yb = (float*)Xk; // alias: Xk+Xv dead after K/V projections (32 MB contiguous)

  hipMemsetAsync(flag, 0, 4, stream);

  cvt_all<<<dim3(4096, 4), 256, 0, stream>>>(query, key_, value, mask, Xq, Xk, Xv, flag);
  cvt_w_all<<<dim3(32, 32, 4), 256, 0, stream>>>(Wq, Wk, Wv, Wo, Wtq, Wtk, Wtv, Wto);

  // Q scale: 1/sqrt(64) * log2(e) -> scores land in exp2 domain
  gemm_qkv<<<dim3(8, 64, 3), 256, 0, stream>>>(Xq, Xk, Xv, Wtq, Wtk, Wtv, Qb, Kb, Vb,
                                               0.125f * LOG2E);

  transpose_v<<<dim3(32, 64), 256, 0, stream>>>(Vb, Vt);

  attn_k<<<dim3(16, 64), 512, 0, stream>>>(Qb, Kb, Vt, mask, flag, attnX);

  gemm_o<<<dim3(8, 64), 256, 0, stream>>>(attnX, Wto, yb, query);

  ln_k<<<8192, 256, 0, stream>>>(yb, gamma, beta, (float*)d_out);
}